// Round 5
// baseline (354.452 us; speedup 1.0000x reference)
//
#include <hip/hip_runtime.h>

#define IN_DIM 256
#define OUT_DIM 128
#define BMG 128           // gemm block tile rows (128x128 tile, 4 waves 2x2)
#define BKG 64

#define BSHIFT 7          // 128 nodes per partition bucket
#define BNODES 128
#define MAXB2 832         // scan width (>= nb2=782), multiple of 4
#define EPT1 15           // partition: edges per thread
#define CHUNK1 3840       // partition: edges per block -> srec 30KB, union 37.5KB
#define CAPB 4736         // per-bucket capacity (mean ~4092, +10 sigma)
#define HCAP 2560         // sort_agg half-bucket capacity (mean ~2046, +11 sigma)
#define RPT 19            // sort_agg: records per thread (19*256=4864 >= CAPB)

typedef __attribute__((ext_vector_type(4))) float floatx4;
typedef __attribute__((ext_vector_type(8))) short shortx8;

static __device__ __forceinline__ unsigned short f2bf(float f) {
  unsigned u = __float_as_uint(f);
  u += 0x7FFFu + ((u >> 16) & 1u);
  return (unsigned short)(u >> 16);
}

// ---------------------------------------------------------------------------
// Prep: Wt[n][k] = bf16(W[k][n]); block 0 also zeroes btail (folds memset).
// ---------------------------------------------------------------------------
__global__ __launch_bounds__(256) void prep_kernel(
    const float* __restrict__ w, unsigned short* __restrict__ wt,
    int* __restrict__ btail, int nb2) {
  const int idx = blockIdx.x * 256 + threadIdx.x;
  const int k = idx >> 7;
  const int n = idx & 127;
  wt[n * IN_DIM + k] = f2bf(w[idx]);
  if (blockIdx.x == 0)
    for (int b = threadIdx.x; b < nb2; b += 256) btail[b] = 0;
}

// ---------------------------------------------------------------------------
// Fused partition + GEMM in ONE dispatch.
// Round-5: CHUNK1 2560->3840 (blocks 1250->834): btail reservation atomics
// (782 hot addresses, serialized per line) drop 33%; longer coalesced flush
// runs. csr2 split into csrx (uint: w15<<17|src17, sign bit of bf16 weight
// is always 0) + csrd (1B bucket-local dst) -- 8B -> 5B per edge.
// ---------------------------------------------------------------------------
__global__ __launch_bounds__(256) void fused_pg_kernel(
    const float* __restrict__ x, const unsigned short* __restrict__ wt,
    unsigned short* __restrict__ xw, int n_nodes,
    const int* __restrict__ esrc, const int* __restrict__ edst,
    const float* __restrict__ ew, int* __restrict__ btail,
    unsigned* __restrict__ csrx, unsigned char* __restrict__ csrd,
    int n_edges, int nb2, int pblocks) {
  __shared__ __align__(16) union {
    struct {
      unsigned short As[BMG][BKG + 8];      // 18.4 KB
      unsigned short Bs[OUT_DIM][BKG + 8];  // 18.4 KB
    } g;
    struct {
      uint2 srec[CHUNK1];  // 30.0 KB
      int hcnt[MAXB2];     // 3.25 KB (hist -> scatter cursor)
      int aux[MAXB2];      // 3.25 KB (loff -> flush base)
      int sh[256];
    } p;
  } sm;

  const int bid = blockIdx.x;
  const int P = pblocks;
  const int G = (int)gridDim.x - pblocks;
  bool is_part;
  int vb;
  if (P <= G) {
    if (bid < 2 * P) { is_part = !(bid & 1); vb = bid >> 1; }
    else             { is_part = false;      vb = bid - P; }
  } else {
    if (bid < 2 * G) { is_part = (bid & 1);  vb = bid >> 1; }
    else             { is_part = true;       vb = bid - G; }
  }

  const int t = threadIdx.x;

  if (is_part) {
    // ---- partition body (counting-sort CHUNK1 edges by 128-node bucket) ----
    const int base = vb * CHUNK1;
    const int cn = min(CHUNK1, n_edges - base);

    for (int b = t; b < MAXB2; b += 256) sm.p.hcnt[b] = 0;
    __syncthreads();

    int dst[EPT1];
    unsigned xpk[EPT1];
#pragma unroll
    for (int i = 0; i < EPT1; ++i) {
      const int idx = t + i * 256;
      if (idx < cn) {
        const int e = base + idx;
        dst[i] = edst[e];
        unsigned wb = __float_as_uint(ew[e]);
        wb += 0x7FFFu + ((wb >> 16) & 1u);
        xpk[i] = ((wb >> 16) << 17) | (unsigned)esrc[e];
        atomicAdd(&sm.p.hcnt[((unsigned)dst[i]) >> BSHIFT], 1);
      } else {
        dst[i] = -1;
      }
    }
    __syncthreads();
    {  // exclusive scan over MAXB2 buckets, 4 slots/thread -> aux = loff
      const int b4 = 4 * t;
      int a0 = 0, a1 = 0, a2 = 0, a3 = 0;
      if (b4 < MAXB2) {
        a0 = sm.p.hcnt[b4];     a1 = sm.p.hcnt[b4 + 1];
        a2 = sm.p.hcnt[b4 + 2]; a3 = sm.p.hcnt[b4 + 3];
      }
      const int s = a0 + a1 + a2 + a3;
      sm.p.sh[t] = s;
      __syncthreads();
      for (int off = 1; off < 256; off <<= 1) {
        const int add = (t >= off) ? sm.p.sh[t - off] : 0;
        __syncthreads();
        sm.p.sh[t] += add;
        __syncthreads();
      }
      if (b4 < MAXB2) {
        int run = sm.p.sh[t] - s;
        sm.p.aux[b4] = run; run += a0;
        sm.p.aux[b4 + 1] = run; run += a1;
        sm.p.aux[b4 + 2] = run; run += a2;
        sm.p.aux[b4 + 3] = run;
      }
    }
    __syncthreads();
    // reserve global runs; hcnt becomes scatter cursor (init = loff);
    // aux becomes flush base (gbase - loff)
    for (int b = t; b < nb2; b += 256) {
      const int c = sm.p.hcnt[b];
      const int lo = sm.p.aux[b];
      int g = 0;
      if (c) g = b * CAPB + atomicAdd(&btail[b], c);
      sm.p.hcnt[b] = lo;
      sm.p.aux[b] = g - lo;
    }
    __syncthreads();
#pragma unroll
    for (int i = 0; i < EPT1; ++i)
      if (dst[i] >= 0) {
        const int bk = ((unsigned)dst[i]) >> BSHIFT;
        const int p = atomicAdd(&sm.p.hcnt[bk], 1);
        sm.p.srec[p] = make_uint2(xpk[i], (unsigned)dst[i]);
      }
    __syncthreads();
    for (int i = t; i < cn; i += 256) {
      const uint2 r = sm.p.srec[i];
      const int bk = r.y >> BSHIFT;
      const size_t pos = (size_t)(sm.p.aux[bk] + i);
      if (pos < (size_t)(bk + 1) * CAPB) {  // clamp (never hit)
        csrx[pos] = r.x;
        csrd[pos] = (unsigned char)(r.y & (BNODES - 1));
      }
    }
  } else {
    // ---- gemm body: 128x128 tile, 4 waves (2x2), wave = 64x64, acc[4][4] ----
    const int wv = t >> 6;
    const int wr = wv >> 1;        // wave row half (0/1)
    const int wc = wv & 1;         // wave col half (0/1)
    const int lane = t & 63;
    const int quad = lane >> 4;
    const int l16 = lane & 15;
    const int row0 = vb * BMG;
    if (row0 >= n_nodes) return;

    floatx4 acc[4][4];
#pragma unroll
    for (int a = 0; a < 4; ++a)
#pragma unroll
      for (int b = 0; b < 4; ++b) acc[a][b] = (floatx4){0.f, 0.f, 0.f, 0.f};

    for (int k0 = 0; k0 < IN_DIM; k0 += BKG) {
      __syncthreads();
      // stage A: 128 rows x 64 k (8192 elems, 32/thread as 8x float4)
#pragma unroll
      for (int i = 0; i < 8; ++i) {
        const int idx = i * 256 + t;
        const int r = idx >> 4;
        const int kq = (idx & 15) * 4;
        int row = row0 + r;
        if (row >= n_nodes) row = n_nodes - 1;
        const float4 v = *(const float4*)(x + (size_t)row * IN_DIM + k0 + kq);
        ushort4 sv;
        sv.x = f2bf(v.x); sv.y = f2bf(v.y); sv.z = f2bf(v.z); sv.w = f2bf(v.w);
        *(ushort4*)&sm.g.As[r][kq] = sv;
      }
      // stage B: 128 cols x 64 k (16B per thread-iter)
#pragma unroll
      for (int i = 0; i < 4; ++i) {
        const int idx16 = i * 256 + t;
        const int n = idx16 >> 3;
        const int off = (idx16 & 7) * 8;
        *(int4*)&sm.g.Bs[n][off] =
            *(const int4*)(wt + (size_t)n * IN_DIM + k0 + off);
      }
      __syncthreads();

#pragma unroll
      for (int kk = 0; kk < BKG; kk += 32) {
        shortx8 af[4];
#pragma unroll
        for (int tm = 0; tm < 4; ++tm)
          af[tm] =
              *(const shortx8*)&sm.g.As[wr * 64 + tm * 16 + l16][kk + quad * 8];
        shortx8 bfr[4];
#pragma unroll
        for (int tn = 0; tn < 4; ++tn)
          bfr[tn] =
              *(const shortx8*)&sm.g.Bs[wc * 64 + tn * 16 + l16][kk + quad * 8];
#pragma unroll
        for (int tm = 0; tm < 4; ++tm)
#pragma unroll
          for (int tn = 0; tn < 4; ++tn)
            acc[tm][tn] = __builtin_amdgcn_mfma_f32_16x16x32_bf16(
                af[tm], bfr[tn], acc[tm][tn], 0, 0, 0);
      }
    }

#pragma unroll
    for (int tm = 0; tm < 4; ++tm)
#pragma unroll
      for (int tn = 0; tn < 4; ++tn)
#pragma unroll
        for (int r = 0; r < 4; ++r) {
          const int grow = row0 + wr * 64 + tm * 16 + quad * 4 + r;
          const int gcol = wc * 64 + tn * 16 + l16;
          if (grow < n_nodes)
            xw[(size_t)grow * OUT_DIM + gcol] = f2bf(acc[tm][tn][r]);
        }
  }
}

// ---------------------------------------------------------------------------
// Sort+aggregate, half-bucket blocks (64 nodes each).
// Round-5: csr2 split into csrx (uint payload, reg-buffered once) + csrd
// (1B dst-local, read twice from global -- 4KB/bucket, L1/L2-hot on the
// second pass). Cuts record bytes 8->5 and, critically, the live register
// buffer 38->19 regs => VGPR back under the 64 cliff (occupancy cap 16->32
// waves/CU). Kept: XCD swizzle, degree-balanced bitonic, depth-8 pipeline.
// ---------------------------------------------------------------------------
struct AggSmem {
  unsigned xs[HCAP];   // 10 KB sorted packed records (own half only)
  int cnt[64];
  int cur[64];
  int sst[64];
  int sen[64];
  int sh[64];          // scan buffer, then sorted (deg<<6|node) keys
};

__global__ __launch_bounds__(256) void sort_agg_kernel(
    const unsigned* __restrict__ csrx, const unsigned char* __restrict__ csrd,
    const int* __restrict__ btail, const unsigned short* __restrict__ xw,
    float* __restrict__ out, int n_nodes) {
  __shared__ __align__(16) AggSmem sm;
  const int t = threadIdx.x;

  // bijective chunked XCD swizzle: logical blocks 2b,2b+1 same XCD
  const int nwg = (int)gridDim.x;
  const int q = nwg >> 3, r = nwg & 7;
  const int xcd = blockIdx.x & 7, bix = blockIdx.x >> 3;
  const int lb = (xcd < r ? xcd * (q + 1) : r * (q + 1) + (xcd - r) * q) + bix;

  const int bucket = lb >> 1;
  const int half = lb & 1;
  const int node0 = (bucket << BSHIFT) + half * 64;
  const size_t S = (size_t)bucket * CAPB;
  const int cnt = min(btail[bucket], CAPB);

  // single csrx scan: buffer this thread's payloads in registers
  unsigned rx[RPT];
#pragma unroll
  for (int k = 0; k < RPT; ++k) {
    const int i = t + k * 256;
    rx[k] = (i < cnt) ? csrx[S + i] : 0u;
  }

  if (t < 64) sm.cnt[t] = 0;
  __syncthreads();
  // pass 1: count own half's nodes from csrd (byte loads, coalesced)
#pragma unroll
  for (int k = 0; k < RPT; ++k) {
    const int i = t + k * 256;
    if (i < cnt) {
      const int yl = csrd[S + i];
      if ((yl >> 6) == half) atomicAdd(&sm.cnt[yl & 63], 1);
    }
  }
  __syncthreads();
  {  // exclusive scan over 64 node counts
    const int s = (t < 64) ? sm.cnt[t] : 0;
    if (t < 64) sm.sh[t] = s;
    __syncthreads();
    for (int off = 1; off < 64; off <<= 1) {
      const int add = (t >= off && t < 64) ? sm.sh[t - off] : 0;
      __syncthreads();
      if (t < 64) sm.sh[t] += add;
      __syncthreads();
    }
    if (t < 64) {
      const int run = sm.sh[t] - s;
      sm.cur[t] = run;
      sm.sst[t] = run;
      sm.sen[t] = run + s;
    }
  }
  __syncthreads();
  // pass 2: scatter own half into sorted LDS order (csrd re-read, ~4KB hot)
#pragma unroll
  for (int k = 0; k < RPT; ++k) {
    const int i = t + k * 256;
    if (i < cnt) {
      const int yl = csrd[S + i];
      if ((yl >> 6) == half) {
        const int p = atomicAdd(&sm.cur[yl & 63], 1);
        if (p < HCAP) sm.xs[p] = rx[k];
      }
    }
  }
  // degree keys for balance sort
  if (t < 64) sm.sh[t] = ((sm.sen[t] - sm.sst[t]) << 6) | t;
  __syncthreads();
  // bitonic sort 64 keys ascending
  for (int kk = 2; kk <= 64; kk <<= 1) {
    for (int jj = kk >> 1; jj > 0; jj >>= 1) {
      if (t < 64) {
        const int ixj = t ^ jj;
        if (ixj > t) {
          const int a = sm.sh[t], b = sm.sh[ixj];
          const bool up = ((t & kk) == 0);
          if ((a > b) == up) { sm.sh[t] = b; sm.sh[ixj] = a; }
        }
      }
      __syncthreads();
    }
  }

  // aggregate: 16 groups x 16 lanes; iteration ii processes sorted ranks
  // [16*ii, 16*ii+16): a wave's 4 groups get adjacent ranks (similar degree)
  const int g = t >> 4;
  const int lane = t & 15;
  const int d8 = lane * 8;  // bf16 dim offset
  const unsigned short* __restrict__ xwd = xw + d8;

#pragma unroll
  for (int ii = 0; ii < 4; ++ii) {
    const int nl = sm.sh[g + (ii << 4)] & 63;
    const int node = node0 + nl;
    if (node >= n_nodes) continue;
    const int j0 = sm.sst[nl];
    const int j1 = min(sm.sen[nl], HCAP);

    float a0 = 0.f, a1 = 0.f, a2 = 0.f, a3 = 0.f;
    float a4 = 0.f, a5 = 0.f, a6 = 0.f, a7 = 0.f;

    int j = j0;
    const int n8 = (j1 - j0) & ~7;
    if (n8 > 0) {
      // software pipeline, depth 8: prefetch batch k+1 while consuming k
      uint4 v[8];
      float wq[8];
#pragma unroll
      for (int u = 0; u < 8; ++u) {
        const unsigned p = sm.xs[j0 + u];
        v[u] = *(const uint4*)(xwd + (size_t)(p & 0x1FFFFu) * OUT_DIM);
        wq[u] = __uint_as_float((p >> 17) << 16);
      }
      for (j = j0 + 8; j < j0 + n8; j += 8) {
        uint4 nv[8];
        float nw[8];
#pragma unroll
        for (int u = 0; u < 8; ++u) {
          const unsigned p = sm.xs[j + u];
          nv[u] = *(const uint4*)(xwd + (size_t)(p & 0x1FFFFu) * OUT_DIM);
          nw[u] = __uint_as_float((p >> 17) << 16);
        }
#pragma unroll
        for (int u = 0; u < 8; ++u) {
          a0 = fmaf(__uint_as_float(v[u].x << 16), wq[u], a0);
          a1 = fmaf(__uint_as_float(v[u].x & 0xFFFF0000u), wq[u], a1);
          a2 = fmaf(__uint_as_float(v[u].y << 16), wq[u], a2);
          a3 = fmaf(__uint_as_float(v[u].y & 0xFFFF0000u), wq[u], a3);
          a4 = fmaf(__uint_as_float(v[u].z << 16), wq[u], a4);
          a5 = fmaf(__uint_as_float(v[u].z & 0xFFFF0000u), wq[u], a5);
          a6 = fmaf(__uint_as_float(v[u].w << 16), wq[u], a6);
          a7 = fmaf(__uint_as_float(v[u].w & 0xFFFF0000u), wq[u], a7);
        }
#pragma unroll
        for (int u = 0; u < 8; ++u) {
          v[u] = nv[u];
          wq[u] = nw[u];
        }
      }
#pragma unroll
      for (int u = 0; u < 8; ++u) {
        a0 = fmaf(__uint_as_float(v[u].x << 16), wq[u], a0);
        a1 = fmaf(__uint_as_float(v[u].x & 0xFFFF0000u), wq[u], a1);
        a2 = fmaf(__uint_as_float(v[u].y << 16), wq[u], a2);
        a3 = fmaf(__uint_as_float(v[u].y & 0xFFFF0000u), wq[u], a3);
        a4 = fmaf(__uint_as_float(v[u].z << 16), wq[u], a4);
        a5 = fmaf(__uint_as_float(v[u].z & 0xFFFF0000u), wq[u], a5);
        a6 = fmaf(__uint_as_float(v[u].w << 16), wq[u], a6);
        a7 = fmaf(__uint_as_float(v[u].w & 0xFFFF0000u), wq[u], a7);
      }
      j = j0 + n8;
    }
    for (; j < j1; ++j) {
      const unsigned p0 = sm.xs[j];
      const float w0 = __uint_as_float((p0 >> 17) << 16);
      const uint4 v0 = *(const uint4*)(xwd + (size_t)(p0 & 0x1FFFFu) * OUT_DIM);
      a0 = fmaf(__uint_as_float(v0.x << 16), w0, a0);
      a1 = fmaf(__uint_as_float(v0.x & 0xFFFF0000u), w0, a1);
      a2 = fmaf(__uint_as_float(v0.y << 16), w0, a2);
      a3 = fmaf(__uint_as_float(v0.y & 0xFFFF0000u), w0, a3);
      a4 = fmaf(__uint_as_float(v0.z << 16), w0, a4);
      a5 = fmaf(__uint_as_float(v0.z & 0xFFFF0000u), w0, a5);
      a6 = fmaf(__uint_as_float(v0.w << 16), w0, a6);
      a7 = fmaf(__uint_as_float(v0.w & 0xFFFF0000u), w0, a7);
    }

    float4 o0, o1;
    o0.x = fmaxf(a0, 0.f); o0.y = fmaxf(a1, 0.f);
    o0.z = fmaxf(a2, 0.f); o0.w = fmaxf(a3, 0.f);
    o1.x = fmaxf(a4, 0.f); o1.y = fmaxf(a5, 0.f);
    o1.z = fmaxf(a6, 0.f); o1.w = fmaxf(a7, 0.f);
    float* orow = out + (size_t)node * OUT_DIM + d8;
    *(float4*)orow = o0;
    *(float4*)(orow + 4) = o1;
  }
}

extern "C" void kernel_launch(void* const* d_in, const int* in_sizes, int n_in,
                              void* d_out, int out_size, void* d_ws,
                              size_t ws_size, hipStream_t stream) {
  const float* x    = (const float*)d_in[0];
  const float* w    = (const float*)d_in[1];
  const float* ew   = (const float*)d_in[2];
  const int*   esrc = (const int*)d_in[3];
  const int*   edst = (const int*)d_in[4];
  float* out = (float*)d_out;

  const int n_edges = in_sizes[2];
  const int n_nodes = out_size / OUT_DIM;
  const int nb2 = (n_nodes + BNODES - 1) >> BSHIFT;  // 782

  // ---- workspace layout ----
  char* p = (char*)d_ws;
  unsigned short* xw = (unsigned short*)p;
  p += (size_t)n_nodes * OUT_DIM * sizeof(unsigned short);
  p = (char*)(((uintptr_t)p + 15) & ~(uintptr_t)15);
  unsigned short* wt = (unsigned short*)p;
  p += (size_t)OUT_DIM * IN_DIM * sizeof(unsigned short);
  p = (char*)(((uintptr_t)p + 15) & ~(uintptr_t)15);
  unsigned* csrx = (unsigned*)p;       p += (size_t)nb2 * CAPB * sizeof(unsigned);
  unsigned char* csrd = (unsigned char*)p;  p += (size_t)nb2 * CAPB;
  p = (char*)(((uintptr_t)p + 15) & ~(uintptr_t)15);
  int* btail = (int*)p;                p += (size_t)nb2 * sizeof(int);

  // prep zeroes btail (block 0) and builds wt; stream order guarantees both
  // before the fused kernel.
  prep_kernel<<<(IN_DIM * OUT_DIM) / 256, 256, 0, stream>>>(w, wt, btail, nb2);

  const int pblocks = (n_edges + CHUNK1 - 1) / CHUNK1;  // 834
  const int gblocks = (n_nodes + BMG - 1) / BMG;        // 782
  fused_pg_kernel<<<pblocks + gblocks, 256, 0, stream>>>(
      x, wt, xw, n_nodes, esrc, edst, ew, btail, csrx, csrd, n_edges, nb2,
      pblocks);

  sort_agg_kernel<<<2 * nb2, 256, 0, stream>>>(csrx, csrd, btail, xw, out,
                                               n_nodes);
}

// Round 6
// 336.382 us; speedup vs baseline: 1.0537x; 1.0537x over previous
//
#include <hip/hip_runtime.h>

#define IN_DIM 256
#define OUT_DIM 128
#define BMG 128           // gemm block tile rows (128x128 tile, 4 waves 2x2)
#define BKG 64

#define BSHIFT 7          // 128 nodes per partition bucket
#define BNODES 128
#define MAXB2 832         // scan width (>= nb2=782), multiple of 4
#define EPT1 10           // partition: edges per thread
#define CHUNK1 2560       // partition: edges per block
#define CAPB 4736         // per-bucket csr2 capacity (mean ~4092, +10 sigma)
#define HCAP 2560         // sort_agg half-bucket capacity (mean ~2046, +11 sigma)
#define RPT 19            // sort_agg: records per thread (19*256=4864 >= CAPB)

typedef __attribute__((ext_vector_type(4))) float floatx4;
typedef __attribute__((ext_vector_type(8))) short shortx8;

static __device__ __forceinline__ unsigned short f2bf(float f) {
  unsigned u = __float_as_uint(f);
  u += 0x7FFFu + ((u >> 16) & 1u);
  return (unsigned short)(u >> 16);
}

// ---------------------------------------------------------------------------
// Prep: Wt[n][k] = bf16(W[k][n]); block 0 also zeroes btail (folds memset).
// ---------------------------------------------------------------------------
__global__ __launch_bounds__(256) void prep_kernel(
    const float* __restrict__ w, unsigned short* __restrict__ wt,
    int* __restrict__ btail, int nb2) {
  const int idx = blockIdx.x * 256 + threadIdx.x;
  const int k = idx >> 7;
  const int n = idx & 127;
  wt[n * IN_DIM + k] = f2bf(w[idx]);
  if (blockIdx.x == 0)
    for (int b = threadIdx.x; b < nb2; b += 256) btail[b] = 0;
}

// ---------------------------------------------------------------------------
// Fused partition + GEMM in ONE dispatch (r4-proven config: CHUNK1 2560,
// uint2 csr2 records — r5's csrx/csrd split + CHUNK1 3840 both regressed
// and are reverted).
// ---------------------------------------------------------------------------
__global__ __launch_bounds__(256) void fused_pg_kernel(
    const float* __restrict__ x, const unsigned short* __restrict__ wt,
    unsigned short* __restrict__ xw, int n_nodes,
    const int* __restrict__ esrc, const int* __restrict__ edst,
    const float* __restrict__ ew, int* __restrict__ btail,
    uint2* __restrict__ csr2, int n_edges, int nb2, int pblocks) {
  __shared__ __align__(16) union {
    struct {
      unsigned short As[BMG][BKG + 8];      // 18.4 KB
      unsigned short Bs[OUT_DIM][BKG + 8];  // 18.4 KB
    } g;
    struct {
      uint2 srec[CHUNK1];  // 20.0 KB
      int hcnt[MAXB2];     // 3.25 KB (hist -> scatter cursor)
      int aux[MAXB2];      // 3.25 KB (loff -> flush base)
      int sh[256];
    } p;
  } sm;

  const int bid = blockIdx.x;
  const int P = pblocks;
  const int G = (int)gridDim.x - pblocks;
  bool is_part;
  int vb;
  if (P <= G) {
    if (bid < 2 * P) { is_part = !(bid & 1); vb = bid >> 1; }
    else             { is_part = false;      vb = bid - P; }
  } else {
    if (bid < 2 * G) { is_part = (bid & 1);  vb = bid >> 1; }
    else             { is_part = true;       vb = bid - G; }
  }

  const int t = threadIdx.x;

  if (is_part) {
    // ---- partition body (counting-sort CHUNK1 edges by 128-node bucket) ----
    const int base = vb * CHUNK1;
    const int cn = min(CHUNK1, n_edges - base);

    for (int b = t; b < MAXB2; b += 256) sm.p.hcnt[b] = 0;
    __syncthreads();

    int dst[EPT1];
    unsigned xpk[EPT1];
#pragma unroll
    for (int i = 0; i < EPT1; ++i) {
      const int idx = t + i * 256;
      if (idx < cn) {
        const int e = base + idx;
        dst[i] = edst[e];
        unsigned wb = __float_as_uint(ew[e]);
        wb += 0x7FFFu + ((wb >> 16) & 1u);
        xpk[i] = ((wb >> 16) << 17) | (unsigned)esrc[e];
        atomicAdd(&sm.p.hcnt[((unsigned)dst[i]) >> BSHIFT], 1);
      } else {
        dst[i] = -1;
      }
    }
    __syncthreads();
    {  // exclusive scan over MAXB2 buckets, 4 slots/thread -> aux = loff
      const int b4 = 4 * t;
      int a0 = 0, a1 = 0, a2 = 0, a3 = 0;
      if (b4 < MAXB2) {
        a0 = sm.p.hcnt[b4];     a1 = sm.p.hcnt[b4 + 1];
        a2 = sm.p.hcnt[b4 + 2]; a3 = sm.p.hcnt[b4 + 3];
      }
      const int s = a0 + a1 + a2 + a3;
      sm.p.sh[t] = s;
      __syncthreads();
      for (int off = 1; off < 256; off <<= 1) {
        const int add = (t >= off) ? sm.p.sh[t - off] : 0;
        __syncthreads();
        sm.p.sh[t] += add;
        __syncthreads();
      }
      if (b4 < MAXB2) {
        int run = sm.p.sh[t] - s;
        sm.p.aux[b4] = run; run += a0;
        sm.p.aux[b4 + 1] = run; run += a1;
        sm.p.aux[b4 + 2] = run; run += a2;
        sm.p.aux[b4 + 3] = run;
      }
    }
    __syncthreads();
    // reserve global runs; hcnt becomes scatter cursor (init = loff);
    // aux becomes flush base (gbase - loff)
    for (int b = t; b < nb2; b += 256) {
      const int c = sm.p.hcnt[b];
      const int lo = sm.p.aux[b];
      int g = 0;
      if (c) g = b * CAPB + atomicAdd(&btail[b], c);
      sm.p.hcnt[b] = lo;
      sm.p.aux[b] = g - lo;
    }
    __syncthreads();
#pragma unroll
    for (int i = 0; i < EPT1; ++i)
      if (dst[i] >= 0) {
        const int bk = ((unsigned)dst[i]) >> BSHIFT;
        const int p = atomicAdd(&sm.p.hcnt[bk], 1);
        sm.p.srec[p] = make_uint2(xpk[i], (unsigned)dst[i]);
      }
    __syncthreads();
    for (int i = t; i < cn; i += 256) {
      const uint2 r = sm.p.srec[i];
      const int bk = r.y >> BSHIFT;
      const size_t pos = (size_t)(sm.p.aux[bk] + i);
      if (pos < (size_t)(bk + 1) * CAPB) csr2[pos] = r;  // clamp (never hit)
    }
  } else {
    // ---- gemm body: 128x128 tile, 4 waves (2x2), wave = 64x64, acc[4][4] ----
    const int wv = t >> 6;
    const int wr = wv >> 1;        // wave row half (0/1)
    const int wc = wv & 1;         // wave col half (0/1)
    const int lane = t & 63;
    const int quad = lane >> 4;
    const int l16 = lane & 15;
    const int row0 = vb * BMG;
    if (row0 >= n_nodes) return;

    floatx4 acc[4][4];
#pragma unroll
    for (int a = 0; a < 4; ++a)
#pragma unroll
      for (int b = 0; b < 4; ++b) acc[a][b] = (floatx4){0.f, 0.f, 0.f, 0.f};

    for (int k0 = 0; k0 < IN_DIM; k0 += BKG) {
      __syncthreads();
      // stage A: 128 rows x 64 k (8192 elems, 32/thread as 8x float4)
#pragma unroll
      for (int i = 0; i < 8; ++i) {
        const int idx = i * 256 + t;
        const int r = idx >> 4;
        const int kq = (idx & 15) * 4;
        int row = row0 + r;
        if (row >= n_nodes) row = n_nodes - 1;
        const float4 v = *(const float4*)(x + (size_t)row * IN_DIM + k0 + kq);
        ushort4 sv;
        sv.x = f2bf(v.x); sv.y = f2bf(v.y); sv.z = f2bf(v.z); sv.w = f2bf(v.w);
        *(ushort4*)&sm.g.As[r][kq] = sv;
      }
      // stage B: 128 cols x 64 k (16B per thread-iter)
#pragma unroll
      for (int i = 0; i < 4; ++i) {
        const int idx16 = i * 256 + t;
        const int n = idx16 >> 3;
        const int off = (idx16 & 7) * 8;
        *(int4*)&sm.g.Bs[n][off] =
            *(const int4*)(wt + (size_t)n * IN_DIM + k0 + off);
      }
      __syncthreads();

#pragma unroll
      for (int kk = 0; kk < BKG; kk += 32) {
        shortx8 af[4];
#pragma unroll
        for (int tm = 0; tm < 4; ++tm)
          af[tm] =
              *(const shortx8*)&sm.g.As[wr * 64 + tm * 16 + l16][kk + quad * 8];
        shortx8 bfr[4];
#pragma unroll
        for (int tn = 0; tn < 4; ++tn)
          bfr[tn] =
              *(const shortx8*)&sm.g.Bs[wc * 64 + tn * 16 + l16][kk + quad * 8];
#pragma unroll
        for (int tm = 0; tm < 4; ++tm)
#pragma unroll
          for (int tn = 0; tn < 4; ++tn)
            acc[tm][tn] = __builtin_amdgcn_mfma_f32_16x16x32_bf16(
                af[tm], bfr[tn], acc[tm][tn], 0, 0, 0);
      }
    }

#pragma unroll
    for (int tm = 0; tm < 4; ++tm)
#pragma unroll
      for (int tn = 0; tn < 4; ++tn)
#pragma unroll
        for (int r = 0; r < 4; ++r) {
          const int grow = row0 + wr * 64 + tm * 16 + quad * 4 + r;
          const int gcol = wc * 64 + tn * 16 + l16;
          if (grow < n_nodes)
            xw[(size_t)grow * OUT_DIM + gcol] = f2bf(acc[tm][tn][r]);
        }
  }
}

// ---------------------------------------------------------------------------
// Sort+aggregate, half-bucket blocks (64 nodes each). r4 structure.
// Round-6 single change: __launch_bounds__(256, 4) -> register budget 128
// VGPR (m69: waves/SIMD halve at 64/128). The gather phase needs ~96-110
// live regs (rec[19]=38 in scan; v[8]+nv[8]=64 + wq/nw=16 + acc 8 in
// gather); at the compiler's default 64-VGPR pin (r3-r5) this SPILLED,
// so the manual depth-8 pipeline never actually ran from registers.
// (256,4) = 16 waves/CU cap = 4 blocks/CU, ~50% occupancy with depth-8.
// ---------------------------------------------------------------------------
struct AggSmem {
  unsigned xs[HCAP];   // 10 KB sorted packed records (own half only)
  int cnt[64];
  int cur[64];
  int sst[64];
  int sen[64];
  int sh[64];          // scan buffer, then sorted (deg<<6|node) keys
};

__global__ __launch_bounds__(256, 4) void sort_agg_kernel(
    const uint2* __restrict__ csr2, const int* __restrict__ btail,
    const unsigned short* __restrict__ xw, float* __restrict__ out,
    int n_nodes) {
  __shared__ __align__(16) AggSmem sm;
  const int t = threadIdx.x;

  // bijective chunked XCD swizzle: logical blocks 2b,2b+1 same XCD
  const int nwg = (int)gridDim.x;
  const int q = nwg >> 3, r = nwg & 7;
  const int xcd = blockIdx.x & 7, bix = blockIdx.x >> 3;
  const int lb = (xcd < r ? xcd * (q + 1) : r * (q + 1) + (xcd - r) * q) + bix;

  const int bucket = lb >> 1;
  const int half = lb & 1;
  const int node0 = (bucket << BSHIFT) + half * 64;
  const size_t S = (size_t)bucket * CAPB;
  const int cnt = min(btail[bucket], CAPB);

  // single global scan: buffer this thread's records in registers
  uint2 rec[RPT];
#pragma unroll
  for (int k = 0; k < RPT; ++k) {
    const int i = t + k * 256;
    rec[k] = (i < cnt) ? csr2[S + i] : make_uint2(0u, 0xFFFFFFFFu);
  }

  if (t < 64) sm.cnt[t] = 0;
  __syncthreads();
  // count own half's nodes (from regs)
#pragma unroll
  for (int k = 0; k < RPT; ++k) {
    const unsigned y = rec[k].y;
    if (y != 0xFFFFFFFFu) {
      const unsigned yl = y & (BNODES - 1);
      if ((int)(yl >> 6) == half) atomicAdd(&sm.cnt[yl & 63], 1);
    }
  }
  __syncthreads();
  {  // exclusive scan over 64 node counts
    const int s = (t < 64) ? sm.cnt[t] : 0;
    if (t < 64) sm.sh[t] = s;
    __syncthreads();
    for (int off = 1; off < 64; off <<= 1) {
      const int add = (t >= off && t < 64) ? sm.sh[t - off] : 0;
      __syncthreads();
      if (t < 64) sm.sh[t] += add;
      __syncthreads();
    }
    if (t < 64) {
      const int run = sm.sh[t] - s;
      sm.cur[t] = run;
      sm.sst[t] = run;
      sm.sen[t] = run + s;
    }
  }
  __syncthreads();
  // scatter own half into sorted LDS order (from regs)
#pragma unroll
  for (int k = 0; k < RPT; ++k) {
    const uint2 rr = rec[k];
    if (rr.y != 0xFFFFFFFFu) {
      const unsigned yl = rr.y & (BNODES - 1);
      if ((int)(yl >> 6) == half) {
        const int p = atomicAdd(&sm.cur[yl & 63], 1);
        if (p < HCAP) sm.xs[p] = rr.x;
      }
    }
  }
  // degree keys for balance sort
  if (t < 64) sm.sh[t] = ((sm.sen[t] - sm.sst[t]) << 6) | t;
  __syncthreads();
  // bitonic sort 64 keys ascending
  for (int kk = 2; kk <= 64; kk <<= 1) {
    for (int jj = kk >> 1; jj > 0; jj >>= 1) {
      if (t < 64) {
        const int ixj = t ^ jj;
        if (ixj > t) {
          const int a = sm.sh[t], b = sm.sh[ixj];
          const bool up = ((t & kk) == 0);
          if ((a > b) == up) { sm.sh[t] = b; sm.sh[ixj] = a; }
        }
      }
      __syncthreads();
    }
  }

  // aggregate: 16 groups x 16 lanes; iteration ii processes sorted ranks
  // [16*ii, 16*ii+16): a wave's 4 groups get adjacent ranks (similar degree)
  const int g = t >> 4;
  const int lane = t & 15;
  const int d8 = lane * 8;  // bf16 dim offset
  const unsigned short* __restrict__ xwd = xw + d8;

#pragma unroll
  for (int ii = 0; ii < 4; ++ii) {
    const int nl = sm.sh[g + (ii << 4)] & 63;
    const int node = node0 + nl;
    if (node >= n_nodes) continue;
    const int j0 = sm.sst[nl];
    const int j1 = min(sm.sen[nl], HCAP);

    float a0 = 0.f, a1 = 0.f, a2 = 0.f, a3 = 0.f;
    float a4 = 0.f, a5 = 0.f, a6 = 0.f, a7 = 0.f;

    int j = j0;
    const int n8 = (j1 - j0) & ~7;
    if (n8 > 0) {
      // software pipeline, depth 8: prefetch batch k+1 while consuming k
      uint4 v[8];
      float wq[8];
#pragma unroll
      for (int u = 0; u < 8; ++u) {
        const unsigned p = sm.xs[j0 + u];
        v[u] = *(const uint4*)(xwd + (size_t)(p & 0x1FFFFu) * OUT_DIM);
        wq[u] = __uint_as_float((p >> 17) << 16);
      }
      for (j = j0 + 8; j < j0 + n8; j += 8) {
        uint4 nv[8];
        float nw[8];
#pragma unroll
        for (int u = 0; u < 8; ++u) {
          const unsigned p = sm.xs[j + u];
          nv[u] = *(const uint4*)(xwd + (size_t)(p & 0x1FFFFu) * OUT_DIM);
          nw[u] = __uint_as_float((p >> 17) << 16);
        }
#pragma unroll
        for (int u = 0; u < 8; ++u) {
          a0 = fmaf(__uint_as_float(v[u].x << 16), wq[u], a0);
          a1 = fmaf(__uint_as_float(v[u].x & 0xFFFF0000u), wq[u], a1);
          a2 = fmaf(__uint_as_float(v[u].y << 16), wq[u], a2);
          a3 = fmaf(__uint_as_float(v[u].y & 0xFFFF0000u), wq[u], a3);
          a4 = fmaf(__uint_as_float(v[u].z << 16), wq[u], a4);
          a5 = fmaf(__uint_as_float(v[u].z & 0xFFFF0000u), wq[u], a5);
          a6 = fmaf(__uint_as_float(v[u].w << 16), wq[u], a6);
          a7 = fmaf(__uint_as_float(v[u].w & 0xFFFF0000u), wq[u], a7);
        }
#pragma unroll
        for (int u = 0; u < 8; ++u) {
          v[u] = nv[u];
          wq[u] = nw[u];
        }
      }
#pragma unroll
      for (int u = 0; u < 8; ++u) {
        a0 = fmaf(__uint_as_float(v[u].x << 16), wq[u], a0);
        a1 = fmaf(__uint_as_float(v[u].x & 0xFFFF0000u), wq[u], a1);
        a2 = fmaf(__uint_as_float(v[u].y << 16), wq[u], a2);
        a3 = fmaf(__uint_as_float(v[u].y & 0xFFFF0000u), wq[u], a3);
        a4 = fmaf(__uint_as_float(v[u].z << 16), wq[u], a4);
        a5 = fmaf(__uint_as_float(v[u].z & 0xFFFF0000u), wq[u], a5);
        a6 = fmaf(__uint_as_float(v[u].w << 16), wq[u], a6);
        a7 = fmaf(__uint_as_float(v[u].w & 0xFFFF0000u), wq[u], a7);
      }
      j = j0 + n8;
    }
    for (; j < j1; ++j) {
      const unsigned p0 = sm.xs[j];
      const float w0 = __uint_as_float((p0 >> 17) << 16);
      const uint4 v0 = *(const uint4*)(xwd + (size_t)(p0 & 0x1FFFFu) * OUT_DIM);
      a0 = fmaf(__uint_as_float(v0.x << 16), w0, a0);
      a1 = fmaf(__uint_as_float(v0.x & 0xFFFF0000u), w0, a1);
      a2 = fmaf(__uint_as_float(v0.y << 16), w0, a2);
      a3 = fmaf(__uint_as_float(v0.y & 0xFFFF0000u), w0, a3);
      a4 = fmaf(__uint_as_float(v0.z << 16), w0, a4);
      a5 = fmaf(__uint_as_float(v0.z & 0xFFFF0000u), w0, a5);
      a6 = fmaf(__uint_as_float(v0.w << 16), w0, a6);
      a7 = fmaf(__uint_as_float(v0.w & 0xFFFF0000u), w0, a7);
    }

    float4 o0, o1;
    o0.x = fmaxf(a0, 0.f); o0.y = fmaxf(a1, 0.f);
    o0.z = fmaxf(a2, 0.f); o0.w = fmaxf(a3, 0.f);
    o1.x = fmaxf(a4, 0.f); o1.y = fmaxf(a5, 0.f);
    o1.z = fmaxf(a6, 0.f); o1.w = fmaxf(a7, 0.f);
    float* orow = out + (size_t)node * OUT_DIM + d8;
    *(float4*)orow = o0;
    *(float4*)(orow + 4) = o1;
  }
}

extern "C" void kernel_launch(void* const* d_in, const int* in_sizes, int n_in,
                              void* d_out, int out_size, void* d_ws,
                              size_t ws_size, hipStream_t stream) {
  const float* x    = (const float*)d_in[0];
  const float* w    = (const float*)d_in[1];
  const float* ew   = (const float*)d_in[2];
  const int*   esrc = (const int*)d_in[3];
  const int*   edst = (const int*)d_in[4];
  float* out = (float*)d_out;

  const int n_edges = in_sizes[2];
  const int n_nodes = out_size / OUT_DIM;
  const int nb2 = (n_nodes + BNODES - 1) >> BSHIFT;  // 782

  // ---- workspace layout ----
  char* p = (char*)d_ws;
  unsigned short* xw = (unsigned short*)p;
  p += (size_t)n_nodes * OUT_DIM * sizeof(unsigned short);
  p = (char*)(((uintptr_t)p + 15) & ~(uintptr_t)15);
  unsigned short* wt = (unsigned short*)p;
  p += (size_t)OUT_DIM * IN_DIM * sizeof(unsigned short);
  p = (char*)(((uintptr_t)p + 15) & ~(uintptr_t)15);
  uint2* csr2 = (uint2*)p;  p += (size_t)nb2 * CAPB * sizeof(uint2);
  int* btail = (int*)p;     p += (size_t)nb2 * sizeof(int);

  // prep zeroes btail (block 0) and builds wt; stream order guarantees both
  // before the fused kernel.
  prep_kernel<<<(IN_DIM * OUT_DIM) / 256, 256, 0, stream>>>(w, wt, btail, nb2);

  const int pblocks = (n_edges + CHUNK1 - 1) / CHUNK1;  // 1250
  const int gblocks = (n_nodes + BMG - 1) / BMG;        // 782
  fused_pg_kernel<<<pblocks + gblocks, 256, 0, stream>>>(
      x, wt, xw, n_nodes, esrc, edst, ew, btail, csr2, n_edges, nb2, pblocks);

  sort_agg_kernel<<<2 * nb2, 256, 0, stream>>>(csr2, btail, xw, out, n_nodes);
}